// Round 5
// baseline (526.246 us; speedup 1.0000x reference)
//
#include <hip/hip_runtime.h>

// hidden = tanh(H @ h + C @ c); comm = hidden. H,C: [64,64]; h,c: [64, 524288].
#define NA 64
#define FD 524288
#define FD2 (FD / 2)   // 262144 float2 columns
#define ROWS 16        // output rows per wave (4 waves/block cover all 64)
#define PF 4           // data prefetch depth (j-steps in flight per wave)

// Round-4 post-mortem: structure was right (spill-free, 73% occ) but still
// latency-bound (VALU 41%, HBM 26%). Two exposed latencies per j-step:
//  (1) 32 discrete stride-256B s_load_dword for coefficients -> lgkmcnt(0)
//      batch stall, sK$ thrashed (4 waves/block touch all 64 rows = 32KB).
//  (2) 1-deep data prefetch -> ~1KB/wave in flight, Little's law gives ~2TB/s.
// Fixes here:
//  (1) stage H^T/C^T in LDS once per block; per j-step a wave reads its 16
//      coefficients as 4x ds_read_b128 at a WAVE-UNIFORM address (broadcast,
//      conflict-free, ~40cy) instead of 32 scalar loads (~300+cy).
//  (2) PF=4 statically-indexed prefetch ring (inner loop fully unrolled so
//      ring slots are compile-time -> stays in VGPRs, no scratch) -> 8KB in
//      flight/wave; ~20 waves/CU -> >=40KB/CU vs ~10KB needed for 6.3TB/s.
// No launch_bounds min-waves (Rounds 2/3: caps trigger demotion/spill).
__global__ __launch_bounds__(256) void linlayer_kernel(
    const float* __restrict__ h, const float* __restrict__ c,
    const float* __restrict__ Hm, const float* __restrict__ Cm,
    float* __restrict__ out)
{
    __shared__ float HT[NA * NA];  // HT[j*64 + i] = H[i][j]
    __shared__ float CT[NA * NA];  // CT[j*64 + i] = C[i][j]

    const int t = threadIdx.x;

    // One-time stage + transpose. Global side coalesced; LDS write has a
    // same-bank conflict (stride-64 float) but it's ~2K cycles once per
    // block vs ~100K in the j-loop -- not worth a swizzle.
#pragma unroll
    for (int k = 0; k < 16; ++k) {
        const int idx = k * 256 + t;
        const int i = idx >> 6, j = idx & 63;
        HT[j * NA + i] = Hm[idx];
        CT[j * NA + i] = Cm[idx];
    }
    __syncthreads();

    const int lane = t & 63;
    int i0 = (t >> 6) * ROWS;                 // wave-uniform row base
    i0 = __builtin_amdgcn_readfirstlane(i0);  // force SGPR

    const int col2 = blockIdx.x * 64 + lane;  // this thread's float2 column

    const float2* __restrict__ h2 = (const float2*)h;
    const float2* __restrict__ c2 = (const float2*)c;
    float2* __restrict__ o2 = (float2*)out;

    float2 acc[ROWS];
#pragma unroll
    for (int i = 0; i < ROWS; ++i) { acc[i].x = 0.f; acc[i].y = 0.f; }

    // PF-deep data ring, statically indexed only.
    float2 hb[PF], cb[PF];
#pragma unroll
    for (int p = 0; p < PF; ++p) {
        hb[p] = h2[(size_t)p * FD2 + col2];
        cb[p] = c2[(size_t)p * FD2 + col2];
    }

    const float4* __restrict__ HT4 = (const float4*)HT;  // [j*16 + i/4]
    const float4* __restrict__ CT4 = (const float4*)CT;
    const int q0 = i0 >> 2;  // wave's float4 offset within a j-row (SGPR)

#pragma unroll 1
    for (int jo = 0; jo < NA; jo += PF) {
#pragma unroll
        for (int p = 0; p < PF; ++p) {           // p static -> ring in VGPRs
            const int j = jo + p;

            // 16+16 coefficients via 4+4 broadcast ds_read_b128.
            float Hc[ROWS], Cc[ROWS];
#pragma unroll
            for (int q = 0; q < ROWS / 4; ++q) {
                const float4 hq = HT4[j * (NA / 4) + q0 + q];
                const float4 cq = CT4[j * (NA / 4) + q0 + q];
                Hc[4 * q + 0] = hq.x; Hc[4 * q + 1] = hq.y;
                Hc[4 * q + 2] = hq.z; Hc[4 * q + 3] = hq.w;
                Cc[4 * q + 0] = cq.x; Cc[4 * q + 1] = cq.y;
                Cc[4 * q + 2] = cq.z; Cc[4 * q + 3] = cq.w;
            }

            const float2 hv = hb[p], cv = cb[p];

            // Refill slot p with row j+PF (wrap reloads rows 0..3 at the
            // tail -- harmless, L1-hot).
            const int jn = (j + PF) & (NA - 1);
            hb[p] = h2[(size_t)jn * FD2 + col2];
            cb[p] = c2[(size_t)jn * FD2 + col2];

#pragma unroll
            for (int i = 0; i < ROWS; ++i) {
                acc[i].x = fmaf(Hc[i], hv.x, fmaf(Cc[i], cv.x, acc[i].x));
                acc[i].y = fmaf(Hc[i], hv.y, fmaf(Cc[i], cv.y, acc[i].y));
            }
        }
    }

    // tanh(x) = 1 - 2/(exp(2x)+1); saturates cleanly, no NaN.
#pragma unroll
    for (int i = 0; i < ROWS; ++i) {
        float2 tv;
        { const float e = __expf(2.0f * acc[i].x); tv.x = 1.0f - 2.0f / (e + 1.0f); }
        { const float e = __expf(2.0f * acc[i].y); tv.y = 1.0f - 2.0f / (e + 1.0f); }
        o2[(size_t)(i0 + i) * FD2 + col2] = tv;        // hidden
        o2[(size_t)(NA + i0 + i) * FD2 + col2] = tv;   // comm (same values)
    }
}

extern "C" void kernel_launch(void* const* d_in, const int* in_sizes, int n_in,
                              void* d_out, int out_size, void* d_ws, size_t ws_size,
                              hipStream_t stream) {
    const float* h  = (const float*)d_in[0];
    const float* c  = (const float*)d_in[1];
    const float* Hm = (const float*)d_in[2];
    const float* Cm = (const float*)d_in[3];
    float* out = (float*)d_out;

    dim3 block(256);
    dim3 grid(FD2 / 64);  // 4096 blocks; block = 64 float2 cols x all 64 rows
    hipLaunchKernelGGL(linlayer_kernel, grid, block, 0, stream,
                       h, c, Hm, Cm, out);
}